// Round 9
// baseline (230.594 us; speedup 1.0000x reference)
//
#include <hip/hip_runtime.h>
#include <hip/hip_bf16.h>
#include <cmath>

#define S_LEN 2048
#define DMODEL 1024
#define NHEADS 16
#define DK 64
#define BATCH 2
#define MTOT (BATCH * S_LEN) /* 4096 */

using short8 = __attribute__((ext_vector_type(8))) short;
using floatx4 = __attribute__((ext_vector_type(4))) float;

// float -> bf16 bits, round-to-nearest-even (scalar path)
__device__ __forceinline__ unsigned short f2b(float f) {
    union { float f; unsigned u; } v; v.f = f;
    unsigned r = v.u + 0x7fff + ((v.u >> 16) & 1);
    return (unsigned short)(r >> 16);
}

// packed 2x float -> bf16x2 (v_cvt_pk_bf16_f32)
__device__ __forceinline__ unsigned pack2(float a, float b) {
    float2 t; t.x = a; t.y = b;
    __hip_bfloat162 h = __float22bfloat162_rn(t);
    union { __hip_bfloat162 h; unsigned u; } v; v.h = h;
    return v.u;
}

// async global->LDS, 16 B/lane. LDS dest is wave-uniform base (+lane*16 by HW).
__device__ __forceinline__ void gload16(const void* g, void* l) {
    __builtin_amdgcn_global_load_lds(
        (const __attribute__((address_space(1))) unsigned int*)g,
        (__attribute__((address_space(3))) unsigned int*)l, 16, 0, 0);
}

#define FENCE() asm volatile("" ::: "memory")

// ---------------------------------------------------------------------------
// Fused preprocessing (single dispatch, blockIdx-range partition):
//   blocks [0, 2048)        : x fp32 -> bf16 cast
//   blocks [2048, 2304)     : RoPE cos/sin tables
//   blocks [2304, 3328)     : W fp32 [k][n] -> bf16 [n][k] transpose
//                             (Wq,Wk head-dims permuted: d -> d/2 or 32+d/2)
// ---------------------------------------------------------------------------
__global__ __launch_bounds__(256) void prep_k(
    const float* __restrict__ x, unsigned short* __restrict__ xb,
    const int* __restrict__ tokpos, float* __restrict__ ct, float* __restrict__ st,
    const float* W0, const float* W1, const float* W2, const float* W3,
    unsigned short* T0, unsigned short* T1, unsigned short* T2, unsigned short* T3) {
    __shared__ float t[64][65];
    const int b = blockIdx.x;
    if (b < 2048) {
        int i = (b * 256 + threadIdx.x) * 8;
        float4 a = *(const float4*)(x + i);
        float4 bb = *(const float4*)(x + i + 4);
        short8 o;
        o[0] = f2b(a.x); o[1] = f2b(a.y); o[2] = f2b(a.z); o[3] = f2b(a.w);
        o[4] = f2b(bb.x); o[5] = f2b(bb.y); o[6] = f2b(bb.z); o[7] = f2b(bb.w);
        *(short8*)(xb + i) = o;
    } else if (b < 2304) {
        int idx = (b - 2048) * 256 + threadIdx.x;  // 0 .. 2048*32-1
        int si = idx >> 5;
        int ip = idx & 31;
        float pos = (float)tokpos[si];
        float inv_freq = powf(10000.0f, -(float)(2 * ip) / 64.0f);
        float ang = pos * inv_freq;
        ct[idx] = cosf(ang);
        st[idx] = sinf(ang);
    } else {
        int id = b - 2304;          // 0..1023
        int z = id >> 8;            // matrix
        int bx = id & 15, by = (id >> 4) & 15;
        const float* W = z == 0 ? W0 : z == 1 ? W1 : z == 2 ? W2 : W3;
        unsigned short* T = z == 0 ? T0 : z == 1 ? T1 : z == 2 ? T2 : T3;
        const bool perm = (z < 2);
        int n0 = bx * 64, k0 = by * 64;
        int rr = threadIdx.x >> 6, cc = threadIdx.x & 63;
#pragma unroll
        for (int r = 0; r < 16; r++) {
            int row = r * 4 + rr;
            t[row][cc] = W[(size_t)(k0 + row) * DMODEL + n0 + cc];
        }
        __syncthreads();
#pragma unroll
        for (int r = 0; r < 16; r++) {
            int row = r * 4 + rr;  // original col within head
            int drow = perm ? (((row & 1) ? 32 : 0) + (row >> 1)) : row;
            T[(size_t)(n0 + drow) * DMODEL + k0 + cc] = f2b(t[cc][row]);
        }
    }
}

// ---------------------------------------------------------------------------
// out += P1 (split-K reduce): 2048 blocks x 256 thr x 8 floats, 48 MB traffic
// ---------------------------------------------------------------------------
__global__ __launch_bounds__(256) void add_k(float* __restrict__ out,
                                             const float* __restrict__ p) {
    int i = (blockIdx.x * 256 + threadIdx.x) * 8;
    float4 a = *(const float4*)(out + i);
    float4 b = *(const float4*)(p + i);
    float4 c = *(const float4*)(out + i + 4);
    float4 d = *(const float4*)(p + i + 4);
    a.x += b.x; a.y += b.y; a.z += b.z; a.w += b.w;
    c.x += d.x; c.y += d.y; c.z += d.z; c.w += d.w;
    *(float4*)(out + i) = a;
    *(float4*)(out + i + 4) = c;
}

// ---------------------------------------------------------------------------
// V[s][d] bf16 -> Vt[b*1024 + d][s] bf16, 64x64 LDS tiles
// ---------------------------------------------------------------------------
__global__ __launch_bounds__(256) void vtrans_k(const unsigned short* __restrict__ V,
                                                unsigned short* __restrict__ Vt) {
    __shared__ unsigned short t[64][72];  // 144 B rows: 16B-aligned, bank-spread
    const int tid = threadIdx.x;
    const int s0 = blockIdx.x * 64, d0 = blockIdx.y * 64;
    const int bb = s0 >> 11;
#pragma unroll
    for (int it = 0; it < 4; it++) {
        int e = (it * 256 + tid) * 4;  // flat ushort4 id: row=s, col=d
        int r = e >> 6, c = e & 63;
        *(ushort4*)&t[r][c] = *(const ushort4*)(V + (size_t)(s0 + r) * DMODEL + d0 + c);
    }
    __syncthreads();
#pragma unroll
    for (int it = 0; it < 4; it++) {
        int e = (it * 256 + tid) * 4;  // flat ushort4 id: row=d, col=s
        int r = e >> 6, c = e & 63;
        ushort4 v;
        v.x = t[c + 0][r]; v.y = t[c + 1][r];
        v.z = t[c + 2][r]; v.w = t[c + 3][r];
        *(ushort4*)(Vt + (size_t)(bb * 1024 + d0 + r) * S_LEN + (s0 & (S_LEN - 1)) + c) = v;
    }
}

// ---------------------------------------------------------------------------
// bf16 MFMA GEMM, 256x256 tile, BK=64, 8 waves (2M x 4N), 8-phase schedule
// with COUNTED vmcnt (T3+T4) + setprio (T5).  (R4 verbatim)
//   kind 0: z selects matrix (Q/K/V), full K. kind 1 (Wo): split-K=2,
//   plain fp32 stores (z=0 -> out, z=1 -> P1; add_k reduces).
// ---------------------------------------------------------------------------
__global__ __launch_bounds__(512, 2) void mm_k(
    const unsigned short* __restrict__ A,
    const unsigned short* __restrict__ Bt0, const unsigned short* __restrict__ Bt1,
    const unsigned short* __restrict__ Bt2,
    void* C0, void* C1, void* C2,
    const float* __restrict__ ct, const float* __restrict__ st, int kind) {
    __shared__ __align__(16) unsigned short blob[10 * 8192];  // 160 KiB

    const int z = blockIdx.z;
    const unsigned short* Bt = (kind == 1) ? Bt0 : (z == 0 ? Bt0 : z == 1 ? Bt1 : Bt2);
    void* C = (kind == 1) ? (z == 0 ? C0 : C1) : (z == 0 ? C0 : z == 1 ? C1 : C2);
    const int mode = (kind == 1) ? 0 : (z == 2 ? 3 : 1);
    const int t0 = (kind == 1) ? z * 8 : 0;   // starting K-tile
    const int NT = (kind == 1) ? 8 : 16;      // K-tiles this block
    // 0.125/ln2: QK^T scaling + exp2-domain softmax, folded into Q
    const float qscale = (z == 0 && kind == 0) ? 0.18033688011112042f : 1.0f;

    const int tid = threadIdx.x;
    const int w = tid >> 6, lane = tid & 63;
    const int l15 = lane & 15, quad = lane >> 4;
    const int wr = w >> 2, wc = w & 3;  // 2 x 4 waves; per-wave out 128x64
    const int m0 = blockIdx.x * 256, n0 = blockIdx.y * 256;  // x=m: XCD A-reuse

    const int rbase = (w >> 1) * 16 + l15;
    const int cbase = (w & 1) * 32 + quad * 8;

    floatx4 acc[8][4];
#pragma unroll
    for (int i = 0; i < 8; i++)
#pragma unroll
        for (int j = 0; j < 4; j++) acc[i][j] = (floatx4){0.f, 0.f, 0.f, 0.f};

    auto stage_half = [&](int h) {   // h relative: K-tile t0 + (h>>2)
        const int ts = t0 + (h >> 2), part = h & 3;
        const int slot = h % 10;
        const unsigned short* src =
            (part < 2 ? A + (((size_t)(m0 + part * 128 + rbase)) << 10)
                      : Bt + (((size_t)(n0 + (part - 2) * 128 + rbase)) << 10))
            + (size_t)ts * 64 + cbase;
        char* d = (char*)blob + slot * 16384 + w * 1024;
        gload16(src, d);                       // group w   (rows rbase)
        gload16(src + (64 << 10), d + 8192);   // group w+8 (rows rbase+64)
    };

#pragma unroll
    for (int h = 0; h < 6; ++h) stage_half(h);
    asm volatile("s_waitcnt vmcnt(4)" ::: "memory");
    FENCE(); __builtin_amdgcn_s_barrier(); FENCE();

    short8 af[4][2];
    for (int t = 0; t < NT; ++t) {
        const int sb = (4 * t) % 10;
        int sA = sb + wr;            if (sA >= 10) sA -= 10;
        int sB = sb + 2 + (wc >> 1); if (sB >= 10) sB -= 10;
        const char* LA = (const char*)blob + sA * 16384;
        const char* LB = (const char*)blob + sB * 16384;
#pragma unroll
        for (int q = 0; q < 4; ++q) {
            const int rh = q >> 1, ch = q & 1;
            if (ch == 0) {  // A-frags for this row-half (reused next phase)
#pragma unroll
                for (int ii = 0; ii < 4; ++ii)
#pragma unroll
                    for (int kh = 0; kh < 2; ++kh)
                        af[ii][kh] = *(const short8*)(LA + ((rh * 4 + ii) * 2 + kh) * 1024 + lane * 16);
            }
            short8 bf[2][2];
#pragma unroll
            for (int jj = 0; jj < 2; ++jj)
#pragma unroll
                for (int kh = 0; kh < 2; ++kh)
                    bf[jj][kh] = *(const short8*)(LB + (((wc & 1) * 4 + ch * 2 + jj) * 2 + kh) * 1024 + lane * 16);
            const int h = 4 * t + q + 6;
            if (h < 4 * NT) stage_half(h);
            if (q == 3) {
                if (t == NT - 2) asm volatile("s_waitcnt vmcnt(0)" ::: "memory");  // tail drain
                else             asm volatile("s_waitcnt vmcnt(4)" ::: "memory");  // counted
            }
            FENCE(); __builtin_amdgcn_s_barrier(); FENCE();
            __builtin_amdgcn_s_setprio(1);
#pragma unroll
            for (int ii = 0; ii < 4; ++ii)
#pragma unroll
                for (int jj = 0; jj < 2; ++jj) {
                    floatx4 a0 = acc[rh * 4 + ii][ch * 2 + jj];
                    a0 = __builtin_amdgcn_mfma_f32_16x16x32_bf16(af[ii][0], bf[jj][0], a0, 0, 0, 0);
                    a0 = __builtin_amdgcn_mfma_f32_16x16x32_bf16(af[ii][1], bf[jj][1], a0, 0, 0, 0);
                    acc[rh * 4 + ii][ch * 2 + jj] = a0;
                }
            __builtin_amdgcn_s_setprio(0);
            FENCE(); __builtin_amdgcn_s_barrier(); FENCE();
        }
    }

    // epilogue: C/D layout col = l15, row = quad*4 + reg
#pragma unroll
    for (int i = 0; i < 8; i++) {
        const int rowb = m0 + wr * 128 + i * 16 + quad * 4;
        if (mode == 0) {
            float* Cf = (float*)C;
#pragma unroll
            for (int j = 0; j < 4; j++) {
                int colb = n0 + wc * 64 + j * 16 + l15;
#pragma unroll
                for (int r = 0; r < 4; r++)
                    Cf[(size_t)(rowb + r) * DMODEL + colb] = acc[i][j][r];
            }
        } else if (mode == 1) {
            unsigned short* Cb = (unsigned short*)C;
#pragma unroll
            for (int jh = 0; jh < 2; jh++) {
                int ip = jh * 16 + l15;                   // pair index within head
                int cole = n0 + wc * 64 + jh * 16 + l15;  // even-member column (d'<32)
#pragma unroll
                for (int r = 0; r < 4; r++) {
                    int row = rowb + r;
                    int si = row & (S_LEN - 1);
                    float c = ct[si * 32 + ip] * qscale;
                    float s = st[si * 32 + ip] * qscale;
                    float e = acc[i][jh][r];       // x_even (permuted weights)
                    float od = acc[i][jh + 2][r];  // x_odd (partner col, same thread)
                    Cb[(size_t)row * DMODEL + cole] = f2b(e * c - od * s);
                    Cb[(size_t)row * DMODEL + cole + 32] = f2b(e * s + od * c);
                }
            }
        } else {
            unsigned short* Cb = (unsigned short*)C;
#pragma unroll
            for (int j = 0; j < 4; j++) {
                int colb = n0 + wc * 64 + j * 16 + l15;
#pragma unroll
                for (int r = 0; r < 4; r++)
                    Cb[(size_t)(rowb + r) * DMODEL + colb] = f2b(acc[i][j][r]);
            }
        }
    }
}

// ---------------------------------------------------------------------------
// Block-cooperative MFMA flash attention, QBLK=256 (8 waves x 32 q, 2
// q-groups/wave) + kv-split balancing.
// R8 diagnosis: per-tile serial constant dominates — each 64-key tile costs
// a barrier + 8 waves x 16KB K/V LDS re-read (~1700 cyc port time) + softmax.
// Doubling q per barrier halves BOTH per q-row: barrier events per bh
// 272 -> 144; each K/V fragment read feeds 2 MFMAs (R6's reuse, but at 8
// waves — R6's failure was 1 wave/SIMD, not the reuse). Ps stays 16 rows/wave
// (q-groups sequential, region reused in-wave) -> LDS 50 KB unchanged.
// Balance: j>=5 q-blocks split into key-halves -> 11 slices/bh, sizes
// {20,16,16,16,14,14,12,12,12,8,4}, 352 blocks (~1.4/CU), longest-first.
// Split slices dump unnormalized U + (m,l); mrg_k combines exactly.
// ---------------------------------------------------------------------------
__global__ __launch_bounds__(512) void attn_k(const unsigned short* __restrict__ Q,
                                              const unsigned short* __restrict__ K,
                                              const unsigned short* __restrict__ Vt,
                                              unsigned short* __restrict__ O,
                                              float* __restrict__ Ub,
                                              float* __restrict__ MLb) {
    __shared__ __align__(16) unsigned short Kblob[2][4096];  // 8 KB/buf
    __shared__ __align__(16) unsigned short Vblob[2][4096];
    __shared__ __align__(16) unsigned short Ps[8][16 * 72];  // per-wave P / O-bounce

    // slice tables (11/bh, desc size 20,16,16,16,14,14,12,12,12,8,4):
    // q-block j (256 rows), key-tile range [k0,k1), partial idx (-1=direct)
    static const int T_j[11]  = {4, 7, 7, 3, 6, 6, 5, 5, 2, 1, 0};
    static const int T_k0[11] = {0, 0, 16, 0, 0, 14, 0, 12, 0, 0, 0};
    static const int T_k1[11] = {20, 16, 32, 16, 14, 28, 12, 24, 12, 8, 4};
    static const int T_sx[11] = {-1, 0, 1, -1, 2, 3, 4, 5, -1, -1, -1};

    const int tid = threadIdx.x;
    const int w = tid >> 6, lane = tid & 63;
    const int l15 = lane & 15, quad = lane >> 4;
    const int idx = blockIdx.x;      // 352 blocks = 11 slices x 32 bh
    const int sr = idx >> 5;
    const int bh = idx & 31;
    const int bb = bh >> 4, h = bh & 15;
    const int j = T_j[sr], kt0 = T_k0[sr], kt1 = T_k1[sr], sx = T_sx[sr];
    const int qb_w = j * 256 + w * 32;  // wave's 32 q-rows

    // Q fragments, both q-groups (B-operand: col=query=l15, k=quad*8)
    short8 aq[2][2];
#pragma unroll
    for (int qg = 0; qg < 2; qg++) {
        const size_t qoff = (size_t)(bb * S_LEN + qb_w + qg * 16 + l15) * DMODEL + h * DK;
        aq[qg][0] = *(const short8*)(Q + qoff + quad * 8);
        aq[qg][1] = *(const short8*)(Q + qoff + 32 + quad * 8);
    }

    floatx4 o[2][4];
#pragma unroll
    for (int qg = 0; qg < 2; qg++)
#pragma unroll
        for (int f = 0; f < 4; f++) o[qg][f] = (floatx4){0.f, 0.f, 0.f, 0.f};
    float mv[2] = {-1e30f, -1e30f}, lv[2] = {0.f, 0.f};

    const unsigned short* Kb = K + (size_t)(bb * S_LEN) * DMODEL + h * DK;
    const unsigned short* Vb = Vt + (size_t)(bb * 1024 + h * DK) * S_LEN;
    unsigned short* ps = &Ps[w][0];

    // stage 64-key K/V tile into blob buffer b (2 gload16/thread, 8 waves)
    auto stage = [&](int b, int kb) {
#pragma unroll
        for (int it = 0; it < 2; it++) {
            int g = it * 8 + w;  // wave-uniform 0..15; 0..7 K-groups, 8..15 V-groups
            if (g < 8) {
                const unsigned short* gp =
                    Kb + (size_t)(kb + (g >> 1) * 16 + l15) * DMODEL + (g & 1) * 32 + quad * 8;
                gload16(gp, (char*)&Kblob[b][0] + g * 1024);
            } else {
                int gv = g - 8;
                const unsigned short* gp =
                    Vb + (size_t)((gv >> 1) * 16 + l15) * S_LEN + kb + (gv & 1) * 32 + quad * 8;
                gload16(gp, (char*)&Vblob[b][0] + gv * 1024);
            }
        }
    };

    stage(0, kt0 * 64);
    for (int kt = kt0; kt < kt1; kt++) {
        const int b = (kt - kt0) & 1;
        const int kb = kt * 64;
        __syncthreads();  // staging of buf b complete; buf b^1 reads done
        if (kt + 1 < kt1) stage(b ^ 1, (kt + 1) * 64);

        // wave skips tiles fully above its 32 causal rows: exact zeros.
        if (kb <= qb_w + 31) {
            // QK^T: S^T[key 64][q 16] per q-group; each kf feeds BOTH groups
            const unsigned short* kbb = &Kblob[b][0];
            floatx4 c[4][2];
            __builtin_amdgcn_s_setprio(1);
#pragma unroll
            for (int g = 0; g < 4; g++) {
                short8 kf0 = *(const short8*)(kbb + (g * 2 + 0) * 512 + lane * 8);
                short8 kf1 = *(const short8*)(kbb + (g * 2 + 1) * 512 + lane * 8);
#pragma unroll
                for (int qg = 0; qg < 2; qg++) {
                    floatx4 t = {0.f, 0.f, 0.f, 0.f};
                    t = __builtin_amdgcn_mfma_f32_16x16x32_bf16(kf0, aq[qg][0], t, 0, 0, 0);
                    c[g][qg] = __builtin_amdgcn_mfma_f32_16x16x32_bf16(kf1, aq[qg][1], t, 0, 0, 0);
                }
            }
            __builtin_amdgcn_s_setprio(0);

            // softmax per q-group (sequential; Ps 16-row region reused)
            short8 pf[2][2];
#pragma unroll
            for (int qg = 0; qg < 2; qg++) {
                const int qbg = qb_w + qg * 16;
                const int qrow = qbg + l15;
                float sv[16];
                if (kb + 63 <= qbg) {  // wave-uniform: whole tile causal-valid
#pragma unroll
                    for (int g = 0; g < 4; g++)
#pragma unroll
                        for (int r = 0; r < 4; r++) sv[g * 4 + r] = c[g][qg][r];
                } else {
#pragma unroll
                    for (int g = 0; g < 4; g++)
#pragma unroll
                        for (int r = 0; r < 4; r++) {
                            int key = kb + g * 16 + quad * 4 + r;
                            sv[g * 4 + r] = (key <= qrow) ? c[g][qg][r] : -1e30f;
                        }
                }
                // tree max (v_max3-friendly, depth 4; fmax exact)
                float t0 = fmaxf(fmaxf(sv[0], sv[1]), sv[2]);
                float t1 = fmaxf(fmaxf(sv[3], sv[4]), sv[5]);
                float t2 = fmaxf(fmaxf(sv[6], sv[7]), sv[8]);
                float t3 = fmaxf(fmaxf(sv[9], sv[10]), sv[11]);
                float t4 = fmaxf(fmaxf(sv[12], sv[13]), sv[14]);
                float mx = fmaxf(fmaxf(fmaxf(t0, t1), fmaxf(t2, t3)), fmaxf(t4, sv[15]));
                mx = fmaxf(mx, __shfl_xor(mx, 16));
                mx = fmaxf(mx, __shfl_xor(mx, 32));

                // wave-uniform rescale skip: alpha==1 exactly when no growth
                if (!__all(mx <= mv[qg])) {
                    float mnew = fmaxf(mv[qg], mx);
                    float alpha = exp2f(mv[qg] - mnew);
                    mv[qg] = mnew;
                    lv[qg] *= alpha;
#pragma unroll
                    for (int f = 0; f < 4; f++) {
                        o[qg][f][0] *= alpha; o[qg][f][1] *= alpha;
                        o[qg][f][2] *= alpha; o[qg][f][3] *= alpha;
                    }
                }
                float p[16], psum = 0.f;
#pragma unroll
                for (int i = 0; i < 16; i++) {
                    p[i] = exp2f(sv[i] - mv[qg]);
                    psum += p[i];
                }
                lv[qg] += psum;

                // P -> LDS (row=q l15, key = g*16+quad*4..+3), stride 72
#pragma unroll
                for (int g = 0; g < 4; g++) {
                    uint2 pk;
                    pk.x = pack2(p[g * 4 + 0], p[g * 4 + 1]);
                    pk.y = pack2(p[g * 4 + 2], p[g * 4 + 3]);
                    *(uint2*)(ps + l15 * 72 + g * 16 + quad * 4) = pk;
                }
                // P^T B-frags (col=q l15, keys quad*8 / +32); read before
                // qg=1 overwrites (in-wave LDS ordering)
                pf[qg][0] = *(const short8*)(ps + l15 * 72 + quad * 8);
                pf[qg][1] = *(const short8*)(ps + l15 * 72 + 32 + quad * 8);
            }

            // PV: each vf feeds BOTH q-groups
            const unsigned short* vbb = &Vblob[b][0];
            __builtin_amdgcn_s_setprio(1);
#pragma unroll
            for (int f = 0; f < 4; f++) {
                short8 vf0 = *(const short8*)(vbb + (f * 2 + 0) * 512 + lane * 8);
                short8 vf1 = *(const short8*)(vbb + (f * 2 + 1) * 512 + lane * 8);
#pragma unroll
                for (int qg = 0; qg < 2; qg++) {
                    o[qg][f] = __builtin_amdgcn_mfma_f32_16x16x32_bf16(vf0, pf[qg][0], o[qg][f], 0, 0, 0);
                    o[qg][f] = __builtin_amdgcn_mfma_f32_16x16x32_bf16(vf1, pf[qg][1], o[qg][f], 0, 0, 0);
                }
            }
            __builtin_amdgcn_s_setprio(0);
        }
    }

    if (sx >= 0) {
        // split slice: dump unnormalized fp32 U + per-lane (m,l) per q-group.
        const int slot = sx * 32 + bh;
#pragma unroll
        for (int qg = 0; qg < 2; qg++) {
            float* up = Ub + (size_t)slot * 16384 + (tid * 2 + qg) * 16;
#pragma unroll
            for (int f = 0; f < 4; f++) {
                float4 v; v.x = o[qg][f][0]; v.y = o[qg][f][1];
                v.z = o[qg][f][2]; v.w = o[qg][f][3];
                *(float4*)(up + f * 4) = v;
            }
            float* mlp = MLb + (size_t)slot * 2048 + (tid * 2 + qg) * 2;
            mlp[0] = mv[qg];
            mlp[1] = lv[qg];
        }
    } else {
        // direct store per q-group: l reduce, un-transpose via LDS (per-wave)
        __syncthreads();  // all waves done with K/V/Ps reads of the loop
#pragma unroll
        for (int qg = 0; qg < 2; qg++) {
            float l = lv[qg];
            l += __shfl_xor(l, 16);
            l += __shfl_xor(l, 32);
            float inv = 1.0f / l;
#pragma unroll
            for (int f = 0; f < 4; f++) {
                uint2 pk;
                pk.x = pack2(o[qg][f][0] * inv, o[qg][f][1] * inv);
                pk.y = pack2(o[qg][f][2] * inv, o[qg][f][3] * inv);
                *(uint2*)(ps + l15 * 72 + f * 16 + quad * 4) = pk;
            }
            short8 r0 = *(const short8*)(ps + l15 * 72 + quad * 8);
            short8 r1 = *(const short8*)(ps + l15 * 72 + 32 + quad * 8);
            size_t obase = (size_t)(bb * S_LEN + qb_w + qg * 16 + l15) * DMODEL + h * DK;
            *(short8*)(O + obase + quad * 8) = r0;
            *(short8*)(O + obase + 32 + quad * 8) = r1;
        }
    }
}

// ---------------------------------------------------------------------------
// Merge kv-split halves of q-blocks j=5,6,7: exact online-softmax combine.
// Grid 96 = 3 pairs x 32 bh, 512 thr: thread owns (q = tid>>1, d-half tid&1),
// q in [0,256). U offset for (q,d):
//   tidq(quad) = (q>>5)*64 + quad*16 + (q&15), qg = (q>>4)&1
//   uoff = (tidq((d>>2)&3)*2 + qg)*16 + (d>>4)*4 + (d&3)
// m: quad=0 entry (quad-uniform); l: sum over 4 quads.
// ---------------------------------------------------------------------------
__global__ __launch_bounds__(512) void mrg_k(const float* __restrict__ Ub,
                                             const float* __restrict__ MLb,
                                             unsigned short* __restrict__ O) {
    const int pid = blockIdx.x;
    const int pair = pid >> 5;        // 0:j7, 1:j6, 2:j5
    const int j = 7 - pair;
    const int bh = pid & 31;
    const int bb = bh >> 4, h = bh & 15;
    const int slotA = (pair * 2) * 32 + bh;
    const int slotB = slotA + 32;
    const int tid = threadIdx.x;
    const int q = tid >> 1, dh = tid & 1;
    const int qg = (q >> 4) & 1;
    const int tq0 = (q >> 5) * 64 + (q & 15);  // quad=0 thread index

    const float* mlA = MLb + (size_t)slotA * 2048;
    const float* mlB = MLb + (size_t)slotB * 2048;
    float mA = mlA[(tq0 * 2 + qg) * 2], mB = mlB[(tq0 * 2 + qg) * 2];
    float lA = 0.f, lB = 0.f;
#pragma unroll
    for (int qd = 0; qd < 4; qd++) {
        int t = ((tq0 + qd * 16) * 2 + qg) * 2 + 1;
        lA += mlA[t];
        lB += mlB[t];
    }
    float m = fmaxf(mA, mB);
    float wA = exp2f(mA - m), wB = exp2f(mB - m);
    float inv = 1.0f / (lA * wA + lB * wB);

    const float* uA = Ub + (size_t)slotA * 16384;
    const float* uB = Ub + (size_t)slotB * 16384;
    unsigned short ov[32];
#pragma unroll
    for (int dd = 0; dd < 32; dd++) {
        int d = dh * 32 + dd;
        int tidq = (q >> 5) * 64 + ((d >> 2) & 3) * 16 + (q & 15);
        int uoff = (tidq * 2 + qg) * 16 + (d >> 4) * 4 + (d & 3);
        float v = (uA[uoff] * wA + uB[uoff] * wB) * inv;
        ov[dd] = f2b(v);
    }
    size_t obase = (size_t)(bb * S_LEN + j * 256 + q) * DMODEL + h * DK + dh * 32;
#pragma unroll
    for (int c = 0; c < 4; c++)
        *(short8*)(O + obase + c * 8) = *(short8*)&ov[c * 8];
}

// ---------------------------------------------------------------------------
extern "C" void kernel_launch(void* const* d_in, const int* in_sizes, int n_in,
                              void* d_out, int out_size, void* d_ws,
                              size_t ws_size, hipStream_t stream) {
    const float* x = (const float*)d_in[0];
    const float* Wq = (const float*)d_in[1];
    const float* Wk = (const float*)d_in[2];
    const float* Wv = (const float*)d_in[3];
    const float* Wo = (const float*)d_in[4];
    const int* tokpos = (const int*)d_in[5];
    float* out = (float*)d_out;

    const size_t MD = (size_t)MTOT * DMODEL;  // 4194304
    const size_t WD = (size_t)DMODEL * DMODEL;
    unsigned short* xb = (unsigned short*)d_ws;
    unsigned short* Wqt = xb + MD;
    unsigned short* Wkt = Wqt + WD;
    unsigned short* Wvt = Wkt + WD;
    unsigned short* Wot = Wvt + WD;
    unsigned short* Q = Wot + WD;
    unsigned short* K = Q + MD;
    unsigned short* V = K + MD;   // after vtrans, reused as attention output O
    unsigned short* Vt = V + MD;  // [b*1024 + d][s]
    float* ct = (float*)(Vt + MD);
    float* st = ct + S_LEN * 32;
    unsigned short* O = V;  // alias: V dead after vtrans_k
    // split-K partial for Wo: 16 MB fp32 over the dead Q+K regions.
    float* P1 = (float*)Q;
    // attn kv-split partials: 14.2 MB over dead xb+Wqt+Wkt+Wvt (dead after
    // QKV mm; Wo mm reads only O (=V region) and Wot).
    float* Ub = (float*)xb;                  // 192 slots x 16384 floats (12.6 MB)
    float* MLb = Ub + (size_t)192 * 16384;   // 192 slots x 2048 floats (1.6 MB)

    // fused preprocessing: cast + rope tables + weight transposes
    prep_k<<<dim3(3328), dim3(256), 0, stream>>>(x, xb, tokpos, ct, st,
                                                 Wq, Wk, Wv, Wo, Wqt, Wkt, Wvt, Wot);

    // Q (RoPE * 0.125/ln2), K (RoPE), V (plain bf16); 256^2 tiles, 8-phase
    mm_k<<<dim3(16, 4, 3), dim3(512), 0, stream>>>(xb, Wqt, Wkt, Wvt,
                                                   (void*)Q, (void*)K, (void*)V, ct, st, 0);
    vtrans_k<<<dim3(64, 16), dim3(256), 0, stream>>>(V, Vt);
    // QBLK=256 kv-split flash attention (352 slices) + exact merge
    attn_k<<<dim3(352), dim3(512), 0, stream>>>(Q, K, Vt, O, Ub, MLb);
    mrg_k<<<dim3(96), dim3(512), 0, stream>>>(Ub, MLb, O);
    // output projection: split-K=2 (128 blocks), plain fp32 stores, reduce
    mm_k<<<dim3(16, 4, 2), dim3(512), 0, stream>>>(O, Wot, Wot, Wot,
                                                   (void*)out, (void*)P1, (void*)P1, ct, st, 1);
    add_k<<<dim3(2048), dim3(256), 0, stream>>>(out, P1);
}

// Round 10
// 208.137 us; speedup vs baseline: 1.1079x; 1.1079x over previous
//
#include <hip/hip_runtime.h>
#include <hip/hip_bf16.h>
#include <cmath>

#define S_LEN 2048
#define DMODEL 1024
#define NHEADS 16
#define DK 64
#define BATCH 2
#define MTOT (BATCH * S_LEN) /* 4096 */

using short8 = __attribute__((ext_vector_type(8))) short;
using floatx4 = __attribute__((ext_vector_type(4))) float;

// float -> bf16 bits, round-to-nearest-even (scalar path)
__device__ __forceinline__ unsigned short f2b(float f) {
    union { float f; unsigned u; } v; v.f = f;
    unsigned r = v.u + 0x7fff + ((v.u >> 16) & 1);
    return (unsigned short)(r >> 16);
}

// packed 2x float -> bf16x2 (v_cvt_pk_bf16_f32)
__device__ __forceinline__ unsigned pack2(float a, float b) {
    float2 t; t.x = a; t.y = b;
    __hip_bfloat162 h = __float22bfloat162_rn(t);
    union { __hip_bfloat162 h; unsigned u; } v; v.h = h;
    return v.u;
}

// async global->LDS, 16 B/lane. LDS dest is wave-uniform base (+lane*16 by HW).
__device__ __forceinline__ void gload16(const void* g, void* l) {
    __builtin_amdgcn_global_load_lds(
        (const __attribute__((address_space(1))) unsigned int*)g,
        (__attribute__((address_space(3))) unsigned int*)l, 16, 0, 0);
}

#define FENCE() asm volatile("" ::: "memory")

// ---------------------------------------------------------------------------
// Fused preprocessing (single dispatch, blockIdx-range partition):
//   blocks [0, 2048)        : x fp32 -> bf16 cast
//   blocks [2048, 2304)     : RoPE cos/sin tables
//   blocks [2304, 3328)     : W fp32 [k][n] -> bf16 [n][k] transpose
//                             (Wq,Wk head-dims permuted: d -> d/2 or 32+d/2)
// ---------------------------------------------------------------------------
__global__ __launch_bounds__(256) void prep_k(
    const float* __restrict__ x, unsigned short* __restrict__ xb,
    const int* __restrict__ tokpos, float* __restrict__ ct, float* __restrict__ st,
    const float* W0, const float* W1, const float* W2, const float* W3,
    unsigned short* T0, unsigned short* T1, unsigned short* T2, unsigned short* T3) {
    __shared__ float t[64][65];
    const int b = blockIdx.x;
    if (b < 2048) {
        int i = (b * 256 + threadIdx.x) * 8;
        float4 a = *(const float4*)(x + i);
        float4 bb = *(const float4*)(x + i + 4);
        short8 o;
        o[0] = f2b(a.x); o[1] = f2b(a.y); o[2] = f2b(a.z); o[3] = f2b(a.w);
        o[4] = f2b(bb.x); o[5] = f2b(bb.y); o[6] = f2b(bb.z); o[7] = f2b(bb.w);
        *(short8*)(xb + i) = o;
    } else if (b < 2304) {
        int idx = (b - 2048) * 256 + threadIdx.x;  // 0 .. 2048*32-1
        int si = idx >> 5;
        int ip = idx & 31;
        float pos = (float)tokpos[si];
        float inv_freq = powf(10000.0f, -(float)(2 * ip) / 64.0f);
        float ang = pos * inv_freq;
        ct[idx] = cosf(ang);
        st[idx] = sinf(ang);
    } else {
        int id = b - 2304;          // 0..1023
        int z = id >> 8;            // matrix
        int bx = id & 15, by = (id >> 4) & 15;
        const float* W = z == 0 ? W0 : z == 1 ? W1 : z == 2 ? W2 : W3;
        unsigned short* T = z == 0 ? T0 : z == 1 ? T1 : z == 2 ? T2 : T3;
        const bool perm = (z < 2);
        int n0 = bx * 64, k0 = by * 64;
        int rr = threadIdx.x >> 6, cc = threadIdx.x & 63;
#pragma unroll
        for (int r = 0; r < 16; r++) {
            int row = r * 4 + rr;
            t[row][cc] = W[(size_t)(k0 + row) * DMODEL + n0 + cc];
        }
        __syncthreads();
#pragma unroll
        for (int r = 0; r < 16; r++) {
            int row = r * 4 + rr;  // original col within head
            int drow = perm ? (((row & 1) ? 32 : 0) + (row >> 1)) : row;
            T[(size_t)(n0 + drow) * DMODEL + k0 + cc] = f2b(t[cc][row]);
        }
    }
}

// ---------------------------------------------------------------------------
// out += P1 (split-K reduce): 2048 blocks x 256 thr x 8 floats, 48 MB traffic
// ---------------------------------------------------------------------------
__global__ __launch_bounds__(256) void add_k(float* __restrict__ out,
                                             const float* __restrict__ p) {
    int i = (blockIdx.x * 256 + threadIdx.x) * 8;
    float4 a = *(const float4*)(out + i);
    float4 b = *(const float4*)(p + i);
    float4 c = *(const float4*)(out + i + 4);
    float4 d = *(const float4*)(p + i + 4);
    a.x += b.x; a.y += b.y; a.z += b.z; a.w += b.w;
    c.x += d.x; c.y += d.y; c.z += d.z; c.w += d.w;
    *(float4*)(out + i) = a;
    *(float4*)(out + i + 4) = c;
}

// ---------------------------------------------------------------------------
// bf16 MFMA GEMM, 256x256 tile, BK=64, 8 waves (2M x 4N), 8-phase schedule
// with COUNTED vmcnt (T3+T4) + setprio (T5).
//   kind 0: z selects matrix (Q/K/V), full K. mode 3 (V, z=2) writes Vt
//     DIRECTLY TRANSPOSED (R10: replaces the vtrans_k dispatch, ~9us saved;
//     bit-identical — same single f2b rounding; 4 s-consecutive acc values
//     per fragment = one ushort4 of a Vt row; per-wave 16 rows x 32B
//     contiguous segments).
//   kind 1 (Wo): split-K=2, plain fp32 stores (z=0 -> out, z=1 -> P1;
//     add_k reduces).
// ---------------------------------------------------------------------------
__global__ __launch_bounds__(512, 2) void mm_k(
    const unsigned short* __restrict__ A,
    const unsigned short* __restrict__ Bt0, const unsigned short* __restrict__ Bt1,
    const unsigned short* __restrict__ Bt2,
    void* C0, void* C1, void* C2,
    const float* __restrict__ ct, const float* __restrict__ st, int kind) {
    __shared__ __align__(16) unsigned short blob[10 * 8192];  // 160 KiB

    const int z = blockIdx.z;
    const unsigned short* Bt = (kind == 1) ? Bt0 : (z == 0 ? Bt0 : z == 1 ? Bt1 : Bt2);
    void* C = (kind == 1) ? (z == 0 ? C0 : C1) : (z == 0 ? C0 : z == 1 ? C1 : C2);
    const int mode = (kind == 1) ? 0 : (z == 2 ? 3 : 1);
    const int t0 = (kind == 1) ? z * 8 : 0;   // starting K-tile
    const int NT = (kind == 1) ? 8 : 16;      // K-tiles this block
    // 0.125/ln2: QK^T scaling + exp2-domain softmax, folded into Q
    const float qscale = (z == 0 && kind == 0) ? 0.18033688011112042f : 1.0f;

    const int tid = threadIdx.x;
    const int w = tid >> 6, lane = tid & 63;
    const int l15 = lane & 15, quad = lane >> 4;
    const int wr = w >> 2, wc = w & 3;  // 2 x 4 waves; per-wave out 128x64
    const int m0 = blockIdx.x * 256, n0 = blockIdx.y * 256;  // x=m: XCD A-reuse

    const int rbase = (w >> 1) * 16 + l15;
    const int cbase = (w & 1) * 32 + quad * 8;

    floatx4 acc[8][4];
#pragma unroll
    for (int i = 0; i < 8; i++)
#pragma unroll
        for (int j = 0; j < 4; j++) acc[i][j] = (floatx4){0.f, 0.f, 0.f, 0.f};

    auto stage_half = [&](int h) {   // h relative: K-tile t0 + (h>>2)
        const int ts = t0 + (h >> 2), part = h & 3;
        const int slot = h % 10;
        const unsigned short* src =
            (part < 2 ? A + (((size_t)(m0 + part * 128 + rbase)) << 10)
                      : Bt + (((size_t)(n0 + (part - 2) * 128 + rbase)) << 10))
            + (size_t)ts * 64 + cbase;
        char* d = (char*)blob + slot * 16384 + w * 1024;
        gload16(src, d);                       // group w   (rows rbase)
        gload16(src + (64 << 10), d + 8192);   // group w+8 (rows rbase+64)
    };

#pragma unroll
    for (int h = 0; h < 6; ++h) stage_half(h);
    asm volatile("s_waitcnt vmcnt(4)" ::: "memory");
    FENCE(); __builtin_amdgcn_s_barrier(); FENCE();

    short8 af[4][2];
    for (int t = 0; t < NT; ++t) {
        const int sb = (4 * t) % 10;
        int sA = sb + wr;            if (sA >= 10) sA -= 10;
        int sB = sb + 2 + (wc >> 1); if (sB >= 10) sB -= 10;
        const char* LA = (const char*)blob + sA * 16384;
        const char* LB = (const char*)blob + sB * 16384;
#pragma unroll
        for (int q = 0; q < 4; ++q) {
            const int rh = q >> 1, ch = q & 1;
            if (ch == 0) {  // A-frags for this row-half (reused next phase)
#pragma unroll
                for (int ii = 0; ii < 4; ++ii)
#pragma unroll
                    for (int kh = 0; kh < 2; ++kh)
                        af[ii][kh] = *(const short8*)(LA + ((rh * 4 + ii) * 2 + kh) * 1024 + lane * 16);
            }
            short8 bf[2][2];
#pragma unroll
            for (int jj = 0; jj < 2; ++jj)
#pragma unroll
                for (int kh = 0; kh < 2; ++kh)
                    bf[jj][kh] = *(const short8*)(LB + (((wc & 1) * 4 + ch * 2 + jj) * 2 + kh) * 1024 + lane * 16);
            const int h = 4 * t + q + 6;
            if (h < 4 * NT) stage_half(h);
            if (q == 3) {
                if (t == NT - 2) asm volatile("s_waitcnt vmcnt(0)" ::: "memory");  // tail drain
                else             asm volatile("s_waitcnt vmcnt(4)" ::: "memory");  // counted
            }
            FENCE(); __builtin_amdgcn_s_barrier(); FENCE();
            __builtin_amdgcn_s_setprio(1);
#pragma unroll
            for (int ii = 0; ii < 4; ++ii)
#pragma unroll
                for (int jj = 0; jj < 2; ++jj) {
                    floatx4 a0 = acc[rh * 4 + ii][ch * 2 + jj];
                    a0 = __builtin_amdgcn_mfma_f32_16x16x32_bf16(af[ii][0], bf[jj][0], a0, 0, 0, 0);
                    a0 = __builtin_amdgcn_mfma_f32_16x16x32_bf16(af[ii][1], bf[jj][1], a0, 0, 0, 0);
                    acc[rh * 4 + ii][ch * 2 + jj] = a0;
                }
            __builtin_amdgcn_s_setprio(0);
            FENCE(); __builtin_amdgcn_s_barrier(); FENCE();
        }
    }

    // epilogue: C/D layout col = l15, row = quad*4 + reg
#pragma unroll
    for (int i = 0; i < 8; i++) {
        const int rowb = m0 + wr * 128 + i * 16 + quad * 4;
        if (mode == 0) {
            float* Cf = (float*)C;
#pragma unroll
            for (int j = 0; j < 4; j++) {
                int colb = n0 + wc * 64 + j * 16 + l15;
#pragma unroll
                for (int r = 0; r < 4; r++)
                    Cf[(size_t)(rowb + r) * DMODEL + colb] = acc[i][j][r];
            }
        } else if (mode == 1) {
            unsigned short* Cb = (unsigned short*)C;
#pragma unroll
            for (int jh = 0; jh < 2; jh++) {
                int ip = jh * 16 + l15;                   // pair index within head
                int cole = n0 + wc * 64 + jh * 16 + l15;  // even-member column (d'<32)
#pragma unroll
                for (int r = 0; r < 4; r++) {
                    int row = rowb + r;
                    int si = row & (S_LEN - 1);
                    float c = ct[si * 32 + ip] * qscale;
                    float s = st[si * 32 + ip] * qscale;
                    float e = acc[i][jh][r];       // x_even (permuted weights)
                    float od = acc[i][jh + 2][r];  // x_odd (partner col, same thread)
                    Cb[(size_t)row * DMODEL + cole] = f2b(e * c - od * s);
                    Cb[(size_t)row * DMODEL + cole + 32] = f2b(e * s + od * c);
                }
            }
        } else {
            // mode 3: V -> Vt[(bb*1024 + d)][s] direct transposed write.
            // acc[i][j][0..3] are 4 s-consecutive values at fixed d -> ushort4.
            unsigned short* Cb = (unsigned short*)C;  // Vt base
            const int bb2 = rowb >> 11;               // batch (same for r=0..3)
            const int si = rowb & (S_LEN - 1);
#pragma unroll
            for (int j = 0; j < 4; j++) {
                int colb = n0 + wc * 64 + j * 16 + l15;  // global d 0..1023
                ushort4 v;
                v.x = f2b(acc[i][j][0]); v.y = f2b(acc[i][j][1]);
                v.z = f2b(acc[i][j][2]); v.w = f2b(acc[i][j][3]);
                *(ushort4*)(Cb + (size_t)(bb2 * 1024 + colb) * S_LEN + si) = v;
            }
        }
    }
}

// ---------------------------------------------------------------------------
// Block-cooperative MFMA flash attention; R4 inner loop VERBATIM, key-loop
// range is a per-block slice [kt0,kt1) for kv-split load shaping. (R8 code,
// measured 52.1 us — best attn config across R1-R9.)
// qt>=10 split into two key-range halves -> slice sizes max 20, 22 slices x
// 32 bh = 704 blocks ~2.75/CU (LDS 50KB -> 3 fit), dispatched descending.
// Split slices write unnormalized fp32 U + per-lane (m,l) partials into the
// dead xb/Wqt/Wkt/Wvt region; mrg_k combines exactly (fp32 reorder only).
// ---------------------------------------------------------------------------
__global__ __launch_bounds__(512) void attn_k(const unsigned short* __restrict__ Q,
                                              const unsigned short* __restrict__ K,
                                              const unsigned short* __restrict__ Vt,
                                              unsigned short* __restrict__ O,
                                              float* __restrict__ Ub,
                                              float* __restrict__ MLb) {
    __shared__ __align__(16) unsigned short Kblob[2][4096];  // 8 KB/buf
    __shared__ __align__(16) unsigned short Vblob[2][4096];
    __shared__ __align__(16) unsigned short Ps[8][16 * 72];  // per-wave P / O-bounce

    // slice tables, descending size {20,18,16,16,16,15,15,14,14,14,13,13,
    // 12,12,12,11,11,10,8,6,4,2}: qt, kt0, kt1, partial-slice idx (-1=direct)
    static const int T_qt[22] = {9, 8, 15, 15, 7, 14, 14, 13, 13, 6, 12,
                                 12, 11, 11, 5, 10, 10, 4, 3, 2, 1, 0};
    static const int T_k0[22] = {0, 0, 0, 16, 0, 0, 15, 0, 14, 0, 0,
                                 13, 0, 12, 0, 0, 11, 0, 0, 0, 0, 0};
    static const int T_k1[22] = {20, 18, 16, 32, 16, 15, 30, 14, 28, 14, 13,
                                 26, 12, 24, 12, 11, 22, 10, 8, 6, 4, 2};
    static const int T_sx[22] = {-1, -1, 10, 11, -1, 8, 9, 6, 7, -1, 4,
                                 5, 2, 3, -1, 0, 1, -1, -1, -1, -1, -1};

    const int tid = threadIdx.x;
    const int w = tid >> 6, lane = tid & 63;
    const int l15 = lane & 15, quad = lane >> 4;
    const int idx = blockIdx.x;      // 704 blocks = 22 slices x 32 bh
    const int sr = idx >> 5;
    const int bh = idx & 31;
    const int bb = bh >> 4, h = bh & 15;
    const int qt = T_qt[sr], kt0 = T_k0[sr], kt1 = T_k1[sr], sx = T_sx[sr];
    const int qbase = qt * 128 + w * 16;
    const int qrow = qbase + l15;

    // Q fragment (B-operand: col=query=l15, k=quad*8), d-halves 0/1
    const size_t qoff = (size_t)(bb * S_LEN + qbase + l15) * DMODEL + h * DK;
    short8 aq0 = *(const short8*)(Q + qoff + quad * 8);
    short8 aq1 = *(const short8*)(Q + qoff + 32 + quad * 8);

    floatx4 o[4];
#pragma unroll
    for (int f = 0; f < 4; f++) o[f] = (floatx4){0.f, 0.f, 0.f, 0.f};
    float mv = -1e30f, lv = 0.f;

    const unsigned short* Kb = K + (size_t)(bb * S_LEN) * DMODEL + h * DK;
    const unsigned short* Vb = Vt + (size_t)(bb * 1024 + h * DK) * S_LEN;
    unsigned short* ps = &Ps[w][0];

    // stage 64-key K/V tile into blob buffer b (2 gload16/thread, 8 waves)
    auto stage = [&](int b, int kb) {
#pragma unroll
        for (int it = 0; it < 2; it++) {
            int g = it * 8 + w;  // wave-uniform 0..15; 0..7 K-groups, 8..15 V-groups
            if (g < 8) {
                const unsigned short* gp =
                    Kb + (size_t)(kb + (g >> 1) * 16 + l15) * DMODEL + (g & 1) * 32 + quad * 8;
                gload16(gp, (char*)&Kblob[b][0] + g * 1024);
            } else {
                int gv = g - 8;
                const unsigned short* gp =
                    Vb + (size_t)((gv >> 1) * 16 + l15) * S_LEN + kb + (gv & 1) * 32 + quad * 8;
                gload16(gp, (char*)&Vblob[b][0] + gv * 1024);
            }
        }
    };

    stage(0, kt0 * 64);
    for (int kt = kt0; kt < kt1; kt++) {
        const int b = (kt - kt0) & 1;
        const int kb = kt * 64;
        __syncthreads();  // staging of buf b complete; buf b^1 reads done
        if (kt + 1 < kt1) stage(b ^ 1, (kt + 1) * 64);

        // waves skip tiles fully above their causal row range: exact zeros.
        if (kb <= qbase + 15) {
            // QK^T: S^T[key 64][q 16]
            const unsigned short* kbb = &Kblob[b][0];
            floatx4 c[4];
            __builtin_amdgcn_s_setprio(1);
#pragma unroll
            for (int g = 0; g < 4; g++) {
                short8 kf0 = *(const short8*)(kbb + (g * 2 + 0) * 512 + lane * 8);
                short8 kf1 = *(const short8*)(kbb + (g * 2 + 1) * 512 + lane * 8);
                floatx4 t = {0.f, 0.f, 0.f, 0.f};
                t = __builtin_amdgcn_mfma_f32_16x16x32_bf16(kf0, aq0, t, 0, 0, 0);
                c[g] = __builtin_amdgcn_mfma_f32_16x16x32_bf16(kf1, aq1, t, 0, 0, 0);
            }
            __builtin_amdgcn_s_setprio(0);

            // softmax over 16 keys/lane (exp2 domain; scores pre-scaled via Q)
            float sv[16];
            if (kb + 63 <= qbase) {  // wave-uniform: whole tile causal-valid
#pragma unroll
                for (int g = 0; g < 4; g++)
#pragma unroll
                    for (int r = 0; r < 4; r++) sv[g * 4 + r] = c[g][r];
            } else {
#pragma unroll
                for (int g = 0; g < 4; g++)
#pragma unroll
                    for (int r = 0; r < 4; r++) {
                        int key = kb + g * 16 + quad * 4 + r;
                        sv[g * 4 + r] = (key <= qrow) ? c[g][r] : -1e30f;
                    }
            }
            // tree max (v_max3-friendly, depth 4; fmax exact)
            float t0 = fmaxf(fmaxf(sv[0], sv[1]), sv[2]);
            float t1 = fmaxf(fmaxf(sv[3], sv[4]), sv[5]);
            float t2 = fmaxf(fmaxf(sv[6], sv[7]), sv[8]);
            float t3 = fmaxf(fmaxf(sv[9], sv[10]), sv[11]);
            float t4 = fmaxf(fmaxf(sv[12], sv[13]), sv[14]);
            float mx = fmaxf(fmaxf(fmaxf(t0, t1), fmaxf(t2, t3)), fmaxf(t4, sv[15]));
            mx = fmaxf(mx, __shfl_xor(mx, 16));
            mx = fmaxf(mx, __shfl_xor(mx, 32));

            // wave-uniform rescale skip: alpha==1 exactly when no growth
            if (!__all(mx <= mv)) {
                float mnew = fmaxf(mv, mx);
                float alpha = exp2f(mv - mnew);
                mv = mnew;
                lv *= alpha;
#pragma unroll
                for (int f = 0; f < 4; f++) {
                    o[f][0] *= alpha; o[f][1] *= alpha;
                    o[f][2] *= alpha; o[f][3] *= alpha;
                }
            }
            float p[16], psum = 0.f;
#pragma unroll
            for (int i = 0; i < 16; i++) {
                p[i] = exp2f(sv[i] - mv);
                psum += p[i];
            }
            lv += psum;  // per-lane partial; cross-quad reduce at end / in merge

            // P -> LDS (row=q l15, key = g*16+quad*4..+3), stride 72 shorts
#pragma unroll
            for (int g = 0; g < 4; g++) {
                uint2 pk;
                pk.x = pack2(p[g * 4 + 0], p[g * 4 + 1]);
                pk.y = pack2(p[g * 4 + 2], p[g * 4 + 3]);
                *(uint2*)(ps + l15 * 72 + g * 16 + quad * 4) = pk;
            }
            // P^T B-frags (col=q l15, keys quad*8 / +32)
            short8 pf0 = *(const short8*)(ps + l15 * 72 + quad * 8);
            short8 pf1 = *(const short8*)(ps + l15 * 72 + 32 + quad * 8);
            const unsigned short* vbb = &Vblob[b][0];
            __builtin_amdgcn_s_setprio(1);
#pragma unroll
            for (int f = 0; f < 4; f++) {
                short8 vf0 = *(const short8*)(vbb + (f * 2 + 0) * 512 + lane * 8);
                short8 vf1 = *(const short8*)(vbb + (f * 2 + 1) * 512 + lane * 8);
                o[f] = __builtin_amdgcn_mfma_f32_16x16x32_bf16(vf0, pf0, o[f], 0, 0, 0);
                o[f] = __builtin_amdgcn_mfma_f32_16x16x32_bf16(vf1, pf1, o[f], 0, 0, 0);
            }
            __builtin_amdgcn_s_setprio(0);
        }
    }

    if (sx >= 0) {
        // split slice: dump unnormalized fp32 U (fragment layout) + per-lane
        // m, l. No quad reduce, no normalize — mrg_k does the exact combine.
        const int slot = sx * 32 + bh;
        float* up = Ub + (size_t)slot * 8192 + tid * 16;
#pragma unroll
        for (int f = 0; f < 4; f++) {
            float4 v; v.x = o[f][0]; v.y = o[f][1]; v.z = o[f][2]; v.w = o[f][3];
            *(float4*)(up + f * 4) = v;
        }
        float* mlp = MLb + (size_t)slot * 1024 + tid * 2;
        mlp[0] = mv;
        mlp[1] = lv;
    } else {
        // direct store: final l reduction across quads, un-transpose via LDS
        lv += __shfl_xor(lv, 16);
        lv += __shfl_xor(lv, 32);
        float inv = 1.0f / lv;
        __syncthreads();  // safe reuse of Ps region
#pragma unroll
        for (int f = 0; f < 4; f++) {
            uint2 pk;
            pk.x = pack2(o[f][0] * inv, o[f][1] * inv);
            pk.y = pack2(o[f][2] * inv, o[f][3] * inv);
            *(uint2*)(ps + l15 * 72 + f * 16 + quad * 4) = pk;  // row=q, d=f*16+quad*4
        }
        short8 r0 = *(const short8*)(ps + l15 * 72 + quad * 8);
        short8 r1 = *(const short8*)(ps + l15 * 72 + 32 + quad * 8);
        size_t obase = (size_t)(bb * S_LEN + qbase + l15) * DMODEL + h * DK;
        *(short8*)(O + obase + quad * 8) = r0;
        *(short8*)(O + obase + 32 + quad * 8) = r1;
    }
}

// ---------------------------------------------------------------------------
// Merge the two kv-split halves of qt>=10: exact online-softmax combine.
// Grid 192 = 6 qt x 32 bh, 256 thr: thread owns (q = tid>>1, d-half tid&1).
// U layout (from attn dump): off(q,d) = ((q>>4)*64 + ((d>>2)&3)*16 + (q&15))
//   *16 + (d>>4)*4 + (d&3).  m per (q): tid quad=0; l = sum over 4 quads.
// ---------------------------------------------------------------------------
__global__ __launch_bounds__(256) void mrg_k(const float* __restrict__ Ub,
                                             const float* __restrict__ MLb,
                                             unsigned short* __restrict__ O) {
    const int pid = blockIdx.x;
    const int qt = 10 + (pid >> 5);
    const int bh = pid & 31;
    const int bb = bh >> 4, h = bh & 15;
    const int slotA = ((qt - 10) * 2) * 32 + bh;
    const int slotB = slotA + 32;
    const int tid = threadIdx.x;
    const int q = tid >> 1, dh = tid & 1;
    const int tq = (q >> 4) * 64 + (q & 15);

    const float* mlA = MLb + (size_t)slotA * 1024;
    const float* mlB = MLb + (size_t)slotB * 1024;
    float mA = mlA[tq * 2], mB = mlB[tq * 2];
    float lA = 0.f, lB = 0.f;
#pragma unroll
    for (int qd = 0; qd < 4; qd++) {
        lA += mlA[(tq + qd * 16) * 2 + 1];
        lB += mlB[(tq + qd * 16) * 2 + 1];
    }
    float m = fmaxf(mA, mB);
    float wA = exp2f(mA - m), wB = exp2f(mB - m);
    float inv = 1.0f / (lA * wA + lB * wB);

    const float* uA = Ub + (size_t)slotA * 8192;
    const float* uB = Ub + (size_t)slotB * 8192;
    unsigned short ov[32];
#pragma unroll
    for (int dd = 0; dd < 32; dd++) {
        int d = dh * 32 + dd;
        int uoff = ((q >> 4) * 64 + ((d >> 2) & 3) * 16 + (q & 15)) * 16 + (d >> 4) * 4 + (d & 3);
        float v = (uA[uoff] * wA + uB[uoff] * wB) * inv;
        ov[dd] = f2b(v);
    }
    size_t obase = (size_t)(bb * S_LEN + qt * 128 + q) * DMODEL + h * DK + dh * 32;
#pragma unroll
    for (int c = 0; c < 4; c++)
        *(short8*)(O + obase + c * 8) = *(short8*)&ov[c * 8];
}

// ---------------------------------------------------------------------------
extern "C" void kernel_launch(void* const* d_in, const int* in_sizes, int n_in,
                              void* d_out, int out_size, void* d_ws,
                              size_t ws_size, hipStream_t stream) {
    const float* x = (const float*)d_in[0];
    const float* Wq = (const float*)d_in[1];
    const float* Wk = (const float*)d_in[2];
    const float* Wv = (const float*)d_in[3];
    const float* Wo = (const float*)d_in[4];
    const int* tokpos = (const int*)d_in[5];
    float* out = (float*)d_out;

    const size_t MD = (size_t)MTOT * DMODEL;  // 4194304
    const size_t WD = (size_t)DMODEL * DMODEL;
    unsigned short* xb = (unsigned short*)d_ws;
    unsigned short* Wqt = xb + MD;
    unsigned short* Wkt = Wqt + WD;
    unsigned short* Wvt = Wkt + WD;
    unsigned short* Wot = Wvt + WD;
    unsigned short* Q = Wot + WD;
    unsigned short* K = Q + MD;
    unsigned short* V = K + MD;   // scratch; used as attention output O
    unsigned short* Vt = V + MD;  // [b*1024 + d][s] — written DIRECTLY by mm_k
    float* ct = (float*)(Vt + MD);
    float* st = ct + S_LEN * 32;
    unsigned short* O = V;
    // split-K partial for Wo: 16 MB fp32 over the dead Q+K regions.
    float* P1 = (float*)Q;
    // attn kv-split partials: 14.2 MB over dead xb+Wqt+Wkt+Wvt (dead after
    // QKV mm; Wo mm reads only O (=V region) and Wot).
    float* Ub = (float*)xb;                 // 384 slots x 8192 floats (12.6 MB)
    float* MLb = Ub + (size_t)384 * 8192;   // 384 slots x 1024 floats (1.6 MB)

    // fused preprocessing: cast + rope tables + weight transposes
    prep_k<<<dim3(3328), dim3(256), 0, stream>>>(x, xb, tokpos, ct, st,
                                                 Wq, Wk, Wv, Wo, Wqt, Wkt, Wvt, Wot);

    // Q (RoPE * 0.125/ln2), K (RoPE), V -> Vt transposed-direct; 256^2 tiles
    mm_k<<<dim3(16, 4, 3), dim3(512), 0, stream>>>(xb, Wqt, Wkt, Wvt,
                                                   (void*)Q, (void*)K, (void*)Vt, ct, st, 0);
    // kv-split flash attention (704 uniform-ish slices) + exact merge
    attn_k<<<dim3(704), dim3(512), 0, stream>>>(Q, K, Vt, O, Ub, MLb);
    mrg_k<<<dim3(192), dim3(256), 0, stream>>>(Ub, MLb, O);
    // output projection: split-K=2 (128 blocks), plain fp32 stores, reduce
    mm_k<<<dim3(16, 4, 2), dim3(512), 0, stream>>>(O, Wot, Wot, Wot,
                                                   (void*)out, (void*)P1, (void*)P1, ct, st, 1);
    add_k<<<dim3(2048), dim3(256), 0, stream>>>(out, P1);
}

// Round 11
// 206.739 us; speedup vs baseline: 1.1154x; 1.0068x over previous
//
#include <hip/hip_runtime.h>
#include <hip/hip_bf16.h>
#include <cmath>

#define S_LEN 2048
#define DMODEL 1024
#define NHEADS 16
#define DK 64
#define BATCH 2
#define MTOT (BATCH * S_LEN) /* 4096 */

using short8 = __attribute__((ext_vector_type(8))) short;
using floatx4 = __attribute__((ext_vector_type(4))) float;

// float -> bf16 bits, round-to-nearest-even (scalar path)
__device__ __forceinline__ unsigned short f2b(float f) {
    union { float f; unsigned u; } v; v.f = f;
    unsigned r = v.u + 0x7fff + ((v.u >> 16) & 1);
    return (unsigned short)(r >> 16);
}

// packed 2x float -> bf16x2 (v_cvt_pk_bf16_f32)
__device__ __forceinline__ unsigned pack2(float a, float b) {
    float2 t; t.x = a; t.y = b;
    __hip_bfloat162 h = __float22bfloat162_rn(t);
    union { __hip_bfloat162 h; unsigned u; } v; v.h = h;
    return v.u;
}

// async global->LDS, 16 B/lane. LDS dest is wave-uniform base (+lane*16 by HW).
__device__ __forceinline__ void gload16(const void* g, void* l) {
    __builtin_amdgcn_global_load_lds(
        (const __attribute__((address_space(1))) unsigned int*)g,
        (__attribute__((address_space(3))) unsigned int*)l, 16, 0, 0);
}

#define FENCE() asm volatile("" ::: "memory")

// ---------------------------------------------------------------------------
// Fused preprocessing (single dispatch, blockIdx-range partition):
//   blocks [0, 2048)        : x fp32 -> bf16 cast
//   blocks [2048, 2304)     : RoPE cos/sin tables
//   blocks [2304, 3328)     : W fp32 [k][n] -> bf16 [n][k] transpose
//                             (Wq,Wk head-dims permuted: d -> d/2 or 32+d/2)
// ---------------------------------------------------------------------------
__global__ __launch_bounds__(256) void prep_k(
    const float* __restrict__ x, unsigned short* __restrict__ xb,
    const int* __restrict__ tokpos, float* __restrict__ ct, float* __restrict__ st,
    const float* W0, const float* W1, const float* W2, const float* W3,
    unsigned short* T0, unsigned short* T1, unsigned short* T2, unsigned short* T3) {
    __shared__ float t[64][65];
    const int b = blockIdx.x;
    if (b < 2048) {
        int i = (b * 256 + threadIdx.x) * 8;
        float4 a = *(const float4*)(x + i);
        float4 bb = *(const float4*)(x + i + 4);
        short8 o;
        o[0] = f2b(a.x); o[1] = f2b(a.y); o[2] = f2b(a.z); o[3] = f2b(a.w);
        o[4] = f2b(bb.x); o[5] = f2b(bb.y); o[6] = f2b(bb.z); o[7] = f2b(bb.w);
        *(short8*)(xb + i) = o;
    } else if (b < 2304) {
        int idx = (b - 2048) * 256 + threadIdx.x;  // 0 .. 2048*32-1
        int si = idx >> 5;
        int ip = idx & 31;
        float pos = (float)tokpos[si];
        float inv_freq = powf(10000.0f, -(float)(2 * ip) / 64.0f);
        float ang = pos * inv_freq;
        ct[idx] = cosf(ang);
        st[idx] = sinf(ang);
    } else {
        int id = b - 2304;          // 0..1023
        int z = id >> 8;            // matrix
        int bx = id & 15, by = (id >> 4) & 15;
        const float* W = z == 0 ? W0 : z == 1 ? W1 : z == 2 ? W2 : W3;
        unsigned short* T = z == 0 ? T0 : z == 1 ? T1 : z == 2 ? T2 : T3;
        const bool perm = (z < 2);
        int n0 = bx * 64, k0 = by * 64;
        int rr = threadIdx.x >> 6, cc = threadIdx.x & 63;
#pragma unroll
        for (int r = 0; r < 16; r++) {
            int row = r * 4 + rr;
            t[row][cc] = W[(size_t)(k0 + row) * DMODEL + n0 + cc];
        }
        __syncthreads();
#pragma unroll
        for (int r = 0; r < 16; r++) {
            int row = r * 4 + rr;  // original col within head
            int drow = perm ? (((row & 1) ? 32 : 0) + (row >> 1)) : row;
            T[(size_t)(n0 + drow) * DMODEL + k0 + cc] = f2b(t[cc][row]);
        }
    }
}

// ---------------------------------------------------------------------------
// out += P1 (split-K reduce): 2048 blocks x 256 thr x 8 floats, 48 MB traffic
// ---------------------------------------------------------------------------
__global__ __launch_bounds__(256) void add_k(float* __restrict__ out,
                                             const float* __restrict__ p) {
    int i = (blockIdx.x * 256 + threadIdx.x) * 8;
    float4 a = *(const float4*)(out + i);
    float4 b = *(const float4*)(p + i);
    float4 c = *(const float4*)(out + i + 4);
    float4 d = *(const float4*)(p + i + 4);
    a.x += b.x; a.y += b.y; a.z += b.z; a.w += b.w;
    c.x += d.x; c.y += d.y; c.z += d.z; c.w += d.w;
    *(float4*)(out + i) = a;
    *(float4*)(out + i + 4) = c;
}

// ---------------------------------------------------------------------------
// bf16 MFMA GEMM, 256x256 tile, BK=64, 8 waves (2M x 4N), 8-phase schedule
// with COUNTED vmcnt (T3+T4) + setprio (T5).
//   kind 0: z selects matrix (Q/K/V), full K. mode 3 (V, z=2) writes Vt
//     transposed via an LDS bounce (R11): R10's direct store was 64x 8B
//     transactions at 4KB stride per instruction and cost ~8us on the QKV
//     dispatch (61.5us, top kernel). Now: acc -> LDS [256][264] padded tile
//     (blob reused; dead after the loop's final barrier), one barrier, then
//     512B-contiguous coalesced row writes. Bit-exact (same single f2b).
//   kind 1 (Wo): split-K=2, plain fp32 stores (z=0 -> out, z=1 -> P1;
//     add_k reduces).
// ---------------------------------------------------------------------------
__global__ __launch_bounds__(512, 2) void mm_k(
    const unsigned short* __restrict__ A,
    const unsigned short* __restrict__ Bt0, const unsigned short* __restrict__ Bt1,
    const unsigned short* __restrict__ Bt2,
    void* C0, void* C1, void* C2,
    const float* __restrict__ ct, const float* __restrict__ st, int kind) {
    __shared__ __align__(16) unsigned short blob[10 * 8192];  // 160 KiB

    const int z = blockIdx.z;
    const unsigned short* Bt = (kind == 1) ? Bt0 : (z == 0 ? Bt0 : z == 1 ? Bt1 : Bt2);
    void* C = (kind == 1) ? (z == 0 ? C0 : C1) : (z == 0 ? C0 : z == 1 ? C1 : C2);
    const int mode = (kind == 1) ? 0 : (z == 2 ? 3 : 1);
    const int t0 = (kind == 1) ? z * 8 : 0;   // starting K-tile
    const int NT = (kind == 1) ? 8 : 16;      // K-tiles this block
    // 0.125/ln2: QK^T scaling + exp2-domain softmax, folded into Q
    const float qscale = (z == 0 && kind == 0) ? 0.18033688011112042f : 1.0f;

    const int tid = threadIdx.x;
    const int w = tid >> 6, lane = tid & 63;
    const int l15 = lane & 15, quad = lane >> 4;
    const int wr = w >> 2, wc = w & 3;  // 2 x 4 waves; per-wave out 128x64
    const int m0 = blockIdx.x * 256, n0 = blockIdx.y * 256;  // x=m: XCD A-reuse

    const int rbase = (w >> 1) * 16 + l15;
    const int cbase = (w & 1) * 32 + quad * 8;

    floatx4 acc[8][4];
#pragma unroll
    for (int i = 0; i < 8; i++)
#pragma unroll
        for (int j = 0; j < 4; j++) acc[i][j] = (floatx4){0.f, 0.f, 0.f, 0.f};

    auto stage_half = [&](int h) {   // h relative: K-tile t0 + (h>>2)
        const int ts = t0 + (h >> 2), part = h & 3;
        const int slot = h % 10;
        const unsigned short* src =
            (part < 2 ? A + (((size_t)(m0 + part * 128 + rbase)) << 10)
                      : Bt + (((size_t)(n0 + (part - 2) * 128 + rbase)) << 10))
            + (size_t)ts * 64 + cbase;
        char* d = (char*)blob + slot * 16384 + w * 1024;
        gload16(src, d);                       // group w   (rows rbase)
        gload16(src + (64 << 10), d + 8192);   // group w+8 (rows rbase+64)
    };

#pragma unroll
    for (int h = 0; h < 6; ++h) stage_half(h);
    asm volatile("s_waitcnt vmcnt(4)" ::: "memory");
    FENCE(); __builtin_amdgcn_s_barrier(); FENCE();

    short8 af[4][2];
    for (int t = 0; t < NT; ++t) {
        const int sb = (4 * t) % 10;
        int sA = sb + wr;            if (sA >= 10) sA -= 10;
        int sB = sb + 2 + (wc >> 1); if (sB >= 10) sB -= 10;
        const char* LA = (const char*)blob + sA * 16384;
        const char* LB = (const char*)blob + sB * 16384;
#pragma unroll
        for (int q = 0; q < 4; ++q) {
            const int rh = q >> 1, ch = q & 1;
            if (ch == 0) {  // A-frags for this row-half (reused next phase)
#pragma unroll
                for (int ii = 0; ii < 4; ++ii)
#pragma unroll
                    for (int kh = 0; kh < 2; ++kh)
                        af[ii][kh] = *(const short8*)(LA + ((rh * 4 + ii) * 2 + kh) * 1024 + lane * 16);
            }
            short8 bf[2][2];
#pragma unroll
            for (int jj = 0; jj < 2; ++jj)
#pragma unroll
                for (int kh = 0; kh < 2; ++kh)
                    bf[jj][kh] = *(const short8*)(LB + (((wc & 1) * 4 + ch * 2 + jj) * 2 + kh) * 1024 + lane * 16);
            const int h = 4 * t + q + 6;
            if (h < 4 * NT) stage_half(h);
            if (q == 3) {
                if (t == NT - 2) asm volatile("s_waitcnt vmcnt(0)" ::: "memory");  // tail drain
                else             asm volatile("s_waitcnt vmcnt(4)" ::: "memory");  // counted
            }
            FENCE(); __builtin_amdgcn_s_barrier(); FENCE();
            __builtin_amdgcn_s_setprio(1);
#pragma unroll
            for (int ii = 0; ii < 4; ++ii)
#pragma unroll
                for (int jj = 0; jj < 2; ++jj) {
                    floatx4 a0 = acc[rh * 4 + ii][ch * 2 + jj];
                    a0 = __builtin_amdgcn_mfma_f32_16x16x32_bf16(af[ii][0], bf[jj][0], a0, 0, 0, 0);
                    a0 = __builtin_amdgcn_mfma_f32_16x16x32_bf16(af[ii][1], bf[jj][1], a0, 0, 0, 0);
                    acc[rh * 4 + ii][ch * 2 + jj] = a0;
                }
            __builtin_amdgcn_s_setprio(0);
            FENCE(); __builtin_amdgcn_s_barrier(); FENCE();
        }
    }

    if (mode == 3) {
        // V -> Vt via LDS transpose. blob is dead (final barrier passed all
        // staging reads). Tile [dlocal 256][slocal 264-pad] ushorts = 135 KB.
        // Phase 1: fragment quads (4 s-consecutive at fixed d) -> ds_write_b64.
        unsigned short* tb = blob;
        const int bb2 = m0 >> 11;              // batch (m0 multiple of 256)
        const int sm0 = m0 & (S_LEN - 1);
#pragma unroll
        for (int i = 0; i < 8; i++) {
            int slocal = wr * 128 + i * 16 + quad * 4;
#pragma unroll
            for (int j = 0; j < 4; j++) {
                int dlocal = wc * 64 + j * 16 + l15;
                ushort4 v;
                v.x = f2b(acc[i][j][0]); v.y = f2b(acc[i][j][1]);
                v.z = f2b(acc[i][j][2]); v.w = f2b(acc[i][j][3]);
                *(ushort4*)(tb + dlocal * 264 + slocal) = v;
            }
        }
        __syncthreads();
        // Phase 2: coalesced row writes — 512 B contiguous per d-row.
        unsigned short* Cb = (unsigned short*)C;  // Vt base
        const int lrow = tid >> 5, lcol = (tid & 31) * 8;
#pragma unroll
        for (int pass = 0; pass < 16; pass++) {
            int d2 = pass * 16 + lrow;
            short8 v = *(const short8*)(tb + d2 * 264 + lcol);
            *(short8*)(Cb + (size_t)(bb2 * 1024 + n0 + d2) * S_LEN + sm0 + lcol) = v;
        }
    } else {
        // epilogue: C/D layout col = l15, row = quad*4 + reg
#pragma unroll
        for (int i = 0; i < 8; i++) {
            const int rowb = m0 + wr * 128 + i * 16 + quad * 4;
            if (mode == 0) {
                float* Cf = (float*)C;
#pragma unroll
                for (int j = 0; j < 4; j++) {
                    int colb = n0 + wc * 64 + j * 16 + l15;
#pragma unroll
                    for (int r = 0; r < 4; r++)
                        Cf[(size_t)(rowb + r) * DMODEL + colb] = acc[i][j][r];
                }
            } else {
                unsigned short* Cb = (unsigned short*)C;
#pragma unroll
                for (int jh = 0; jh < 2; jh++) {
                    int ip = jh * 16 + l15;                   // pair index within head
                    int cole = n0 + wc * 64 + jh * 16 + l15;  // even-member column (d'<32)
#pragma unroll
                    for (int r = 0; r < 4; r++) {
                        int row = rowb + r;
                        int si = row & (S_LEN - 1);
                        float c = ct[si * 32 + ip] * qscale;
                        float s = st[si * 32 + ip] * qscale;
                        float e = acc[i][jh][r];       // x_even (permuted weights)
                        float od = acc[i][jh + 2][r];  // x_odd (partner col, same thread)
                        Cb[(size_t)row * DMODEL + cole] = f2b(e * c - od * s);
                        Cb[(size_t)row * DMODEL + cole + 32] = f2b(e * s + od * c);
                    }
                }
            }
        }
    }
}

// ---------------------------------------------------------------------------
// Block-cooperative MFMA flash attention; R4 inner loop VERBATIM, key-loop
// range is a per-block slice [kt0,kt1) for kv-split load shaping. (R8 code,
// measured 52.1 us — best attn config across R1-R9.)
// qt>=10 split into two key-range halves -> slice sizes max 20, 22 slices x
// 32 bh = 704 blocks ~2.75/CU (LDS 50KB -> 3 fit), dispatched descending.
// Split slices write unnormalized fp32 U + per-lane (m,l) partials into the
// dead xb/Wqt/Wkt/Wvt region; mrg_k combines exactly (fp32 reorder only).
// ---------------------------------------------------------------------------
__global__ __launch_bounds__(512) void attn_k(const unsigned short* __restrict__ Q,
                                              const unsigned short* __restrict__ K,
                                              const unsigned short* __restrict__ Vt,
                                              unsigned short* __restrict__ O,
                                              float* __restrict__ Ub,
                                              float* __restrict__ MLb) {
    __shared__ __align__(16) unsigned short Kblob[2][4096];  // 8 KB/buf
    __shared__ __align__(16) unsigned short Vblob[2][4096];
    __shared__ __align__(16) unsigned short Ps[8][16 * 72];  // per-wave P / O-bounce

    // slice tables, descending size {20,18,16,16,16,15,15,14,14,14,13,13,
    // 12,12,12,11,11,10,8,6,4,2}: qt, kt0, kt1, partial-slice idx (-1=direct)
    static const int T_qt[22] = {9, 8, 15, 15, 7, 14, 14, 13, 13, 6, 12,
                                 12, 11, 11, 5, 10, 10, 4, 3, 2, 1, 0};
    static const int T_k0[22] = {0, 0, 0, 16, 0, 0, 15, 0, 14, 0, 0,
                                 13, 0, 12, 0, 0, 11, 0, 0, 0, 0, 0};
    static const int T_k1[22] = {20, 18, 16, 32, 16, 15, 30, 14, 28, 14, 13,
                                 26, 12, 24, 12, 11, 22, 10, 8, 6, 4, 2};
    static const int T_sx[22] = {-1, -1, 10, 11, -1, 8, 9, 6, 7, -1, 4,
                                 5, 2, 3, -1, 0, 1, -1, -1, -1, -1, -1};

    const int tid = threadIdx.x;
    const int w = tid >> 6, lane = tid & 63;
    const int l15 = lane & 15, quad = lane >> 4;
    const int idx = blockIdx.x;      // 704 blocks = 22 slices x 32 bh
    const int sr = idx >> 5;
    const int bh = idx & 31;
    const int bb = bh >> 4, h = bh & 15;
    const int qt = T_qt[sr], kt0 = T_k0[sr], kt1 = T_k1[sr], sx = T_sx[sr];
    const int qbase = qt * 128 + w * 16;
    const int qrow = qbase + l15;

    // Q fragment (B-operand: col=query=l15, k=quad*8), d-halves 0/1
    const size_t qoff = (size_t)(bb * S_LEN + qbase + l15) * DMODEL + h * DK;
    short8 aq0 = *(const short8*)(Q + qoff + quad * 8);
    short8 aq1 = *(const short8*)(Q + qoff + 32 + quad * 8);

    floatx4 o[4];
#pragma unroll
    for (int f = 0; f < 4; f++) o[f] = (floatx4){0.f, 0.f, 0.f, 0.f};
    float mv = -1e30f, lv = 0.f;

    const unsigned short* Kb = K + (size_t)(bb * S_LEN) * DMODEL + h * DK;
    const unsigned short* Vb = Vt + (size_t)(bb * 1024 + h * DK) * S_LEN;
    unsigned short* ps = &Ps[w][0];

    // stage 64-key K/V tile into blob buffer b (2 gload16/thread, 8 waves)
    auto stage = [&](int b, int kb) {
#pragma unroll
        for (int it = 0; it < 2; it++) {
            int g = it * 8 + w;  // wave-uniform 0..15; 0..7 K-groups, 8..15 V-groups
            if (g < 8) {
                const unsigned short* gp =
                    Kb + (size_t)(kb + (g >> 1) * 16 + l15) * DMODEL + (g & 1) * 32 + quad * 8;
                gload16(gp, (char*)&Kblob[b][0] + g * 1024);
            } else {
                int gv = g - 8;
                const unsigned short* gp =
                    Vb + (size_t)((gv >> 1) * 16 + l15) * S_LEN + kb + (gv & 1) * 32 + quad * 8;
                gload16(gp, (char*)&Vblob[b][0] + gv * 1024);
            }
        }
    };

    stage(0, kt0 * 64);
    for (int kt = kt0; kt < kt1; kt++) {
        const int b = (kt - kt0) & 1;
        const int kb = kt * 64;
        __syncthreads();  // staging of buf b complete; buf b^1 reads done
        if (kt + 1 < kt1) stage(b ^ 1, (kt + 1) * 64);

        // waves skip tiles fully above their causal row range: exact zeros.
        if (kb <= qbase + 15) {
            // QK^T: S^T[key 64][q 16]
            const unsigned short* kbb = &Kblob[b][0];
            floatx4 c[4];
            __builtin_amdgcn_s_setprio(1);
#pragma unroll
            for (int g = 0; g < 4; g++) {
                short8 kf0 = *(const short8*)(kbb + (g * 2 + 0) * 512 + lane * 8);
                short8 kf1 = *(const short8*)(kbb + (g * 2 + 1) * 512 + lane * 8);
                floatx4 t = {0.f, 0.f, 0.f, 0.f};
                t = __builtin_amdgcn_mfma_f32_16x16x32_bf16(kf0, aq0, t, 0, 0, 0);
                c[g] = __builtin_amdgcn_mfma_f32_16x16x32_bf16(kf1, aq1, t, 0, 0, 0);
            }
            __builtin_amdgcn_s_setprio(0);

            // softmax over 16 keys/lane (exp2 domain; scores pre-scaled via Q)
            float sv[16];
            if (kb + 63 <= qbase) {  // wave-uniform: whole tile causal-valid
#pragma unroll
                for (int g = 0; g < 4; g++)
#pragma unroll
                    for (int r = 0; r < 4; r++) sv[g * 4 + r] = c[g][r];
            } else {
#pragma unroll
                for (int g = 0; g < 4; g++)
#pragma unroll
                    for (int r = 0; r < 4; r++) {
                        int key = kb + g * 16 + quad * 4 + r;
                        sv[g * 4 + r] = (key <= qrow) ? c[g][r] : -1e30f;
                    }
            }
            // tree max (v_max3-friendly, depth 4; fmax exact)
            float t0 = fmaxf(fmaxf(sv[0], sv[1]), sv[2]);
            float t1 = fmaxf(fmaxf(sv[3], sv[4]), sv[5]);
            float t2 = fmaxf(fmaxf(sv[6], sv[7]), sv[8]);
            float t3 = fmaxf(fmaxf(sv[9], sv[10]), sv[11]);
            float t4 = fmaxf(fmaxf(sv[12], sv[13]), sv[14]);
            float mx = fmaxf(fmaxf(fmaxf(t0, t1), fmaxf(t2, t3)), fmaxf(t4, sv[15]));
            mx = fmaxf(mx, __shfl_xor(mx, 16));
            mx = fmaxf(mx, __shfl_xor(mx, 32));

            // wave-uniform rescale skip: alpha==1 exactly when no growth
            if (!__all(mx <= mv)) {
                float mnew = fmaxf(mv, mx);
                float alpha = exp2f(mv - mnew);
                mv = mnew;
                lv *= alpha;
#pragma unroll
                for (int f = 0; f < 4; f++) {
                    o[f][0] *= alpha; o[f][1] *= alpha;
                    o[f][2] *= alpha; o[f][3] *= alpha;
                }
            }
            float p[16], psum = 0.f;
#pragma unroll
            for (int i = 0; i < 16; i++) {
                p[i] = exp2f(sv[i] - mv);
                psum += p[i];
            }
            lv += psum;  // per-lane partial; cross-quad reduce at end / in merge

            // P -> LDS (row=q l15, key = g*16+quad*4..+3), stride 72 shorts
#pragma unroll
            for (int g = 0; g < 4; g++) {
                uint2 pk;
                pk.x = pack2(p[g * 4 + 0], p[g * 4 + 1]);
                pk.y = pack2(p[g * 4 + 2], p[g * 4 + 3]);
                *(uint2*)(ps + l15 * 72 + g * 16 + quad * 4) = pk;
            }
            // P^T B-frags (col=q l15, keys quad*8 / +32)
            short8 pf0 = *(const short8*)(ps + l15 * 72 + quad * 8);
            short8 pf1 = *(const short8*)(ps + l15 * 72 + 32 + quad * 8);
            const unsigned short* vbb = &Vblob[b][0];
            __builtin_amdgcn_s_setprio(1);
#pragma unroll
            for (int f = 0; f < 4; f++) {
                short8 vf0 = *(const short8*)(vbb + (f * 2 + 0) * 512 + lane * 8);
                short8 vf1 = *(const short8*)(vbb + (f * 2 + 1) * 512 + lane * 8);
                o[f] = __builtin_amdgcn_mfma_f32_16x16x32_bf16(vf0, pf0, o[f], 0, 0, 0);
                o[f] = __builtin_amdgcn_mfma_f32_16x16x32_bf16(vf1, pf1, o[f], 0, 0, 0);
            }
            __builtin_amdgcn_s_setprio(0);
        }
    }

    if (sx >= 0) {
        // split slice: dump unnormalized fp32 U (fragment layout) + per-lane
        // m, l. No quad reduce, no normalize — mrg_k does the exact combine.
        const int slot = sx * 32 + bh;
        float* up = Ub + (size_t)slot * 8192 + tid * 16;
#pragma unroll
        for (int f = 0; f < 4; f++) {
            float4 v; v.x = o[f][0]; v.y = o[f][1]; v.z = o[f][2]; v.w = o[f][3];
            *(float4*)(up + f * 4) = v;
        }
        float* mlp = MLb + (size_t)slot * 1024 + tid * 2;
        mlp[0] = mv;
        mlp[1] = lv;
    } else {
        // direct store: final l reduction across quads, un-transpose via LDS
        lv += __shfl_xor(lv, 16);
        lv += __shfl_xor(lv, 32);
        float inv = 1.0f / lv;
        __syncthreads();  // safe reuse of Ps region
#pragma unroll
        for (int f = 0; f < 4; f++) {
            uint2 pk;
            pk.x = pack2(o[f][0] * inv, o[f][1] * inv);
            pk.y = pack2(o[f][2] * inv, o[f][3] * inv);
            *(uint2*)(ps + l15 * 72 + f * 16 + quad * 4) = pk;  // row=q, d=f*16+quad*4
        }
        short8 r0 = *(const short8*)(ps + l15 * 72 + quad * 8);
        short8 r1 = *(const short8*)(ps + l15 * 72 + 32 + quad * 8);
        size_t obase = (size_t)(bb * S_LEN + qbase + l15) * DMODEL + h * DK;
        *(short8*)(O + obase + quad * 8) = r0;
        *(short8*)(O + obase + 32 + quad * 8) = r1;
    }
}

// ---------------------------------------------------------------------------
// Merge the two kv-split halves of qt>=10: exact online-softmax combine.
// Grid 192 = 6 qt x 32 bh, 256 thr: thread owns (q = tid>>1, d-half tid&1).
// U layout (from attn dump): off(q,d) = ((q>>4)*64 + ((d>>2)&3)*16 + (q&15))
//   *16 + (d>>4)*4 + (d&3).  m per (q): tid quad=0; l = sum over 4 quads.
// ---------------------------------------------------------------------------
__global__ __launch_bounds__(256) void mrg_k(const float* __restrict__ Ub,
                                             const float* __restrict__ MLb,
                                             unsigned short* __restrict__ O) {
    const int pid = blockIdx.x;
    const int qt = 10 + (pid >> 5);
    const int bh = pid & 31;
    const int bb = bh >> 4, h = bh & 15;
    const int slotA = ((qt - 10) * 2) * 32 + bh;
    const int slotB = slotA + 32;
    const int tid = threadIdx.x;
    const int q = tid >> 1, dh = tid & 1;
    const int tq = (q >> 4) * 64 + (q & 15);

    const float* mlA = MLb + (size_t)slotA * 1024;
    const float* mlB = MLb + (size_t)slotB * 1024;
    float mA = mlA[tq * 2], mB = mlB[tq * 2];
    float lA = 0.f, lB = 0.f;
#pragma unroll
    for (int qd = 0; qd < 4; qd++) {
        lA += mlA[(tq + qd * 16) * 2 + 1];
        lB += mlB[(tq + qd * 16) * 2 + 1];
    }
    float m = fmaxf(mA, mB);
    float wA = exp2f(mA - m), wB = exp2f(mB - m);
    float inv = 1.0f / (lA * wA + lB * wB);

    const float* uA = Ub + (size_t)slotA * 8192;
    const float* uB = Ub + (size_t)slotB * 8192;
    unsigned short ov[32];
#pragma unroll
    for (int dd = 0; dd < 32; dd++) {
        int d = dh * 32 + dd;
        int uoff = ((q >> 4) * 64 + ((d >> 2) & 3) * 16 + (q & 15)) * 16 + (d >> 4) * 4 + (d & 3);
        float v = (uA[uoff] * wA + uB[uoff] * wB) * inv;
        ov[dd] = f2b(v);
    }
    size_t obase = (size_t)(bb * S_LEN + qt * 128 + q) * DMODEL + h * DK + dh * 32;
#pragma unroll
    for (int c = 0; c < 4; c++)
        *(short8*)(O + obase + c * 8) = *(short8*)&ov[c * 8];
}

// ---------------------------------------------------------------------------
extern "C" void kernel_launch(void* const* d_in, const int* in_sizes, int n_in,
                              void* d_out, int out_size, void* d_ws,
                              size_t ws_size, hipStream_t stream) {
    const float* x = (const float*)d_in[0];
    const float* Wq = (const float*)d_in[1];
    const float* Wk = (const float*)d_in[2];
    const float* Wv = (const float*)d_in[3];
    const float* Wo = (const float*)d_in[4];
    const int* tokpos = (const int*)d_in[5];
    float* out = (float*)d_out;

    const size_t MD = (size_t)MTOT * DMODEL;  // 4194304
    const size_t WD = (size_t)DMODEL * DMODEL;
    unsigned short* xb = (unsigned short*)d_ws;
    unsigned short* Wqt = xb + MD;
    unsigned short* Wkt = Wqt + WD;
    unsigned short* Wvt = Wkt + WD;
    unsigned short* Wot = Wvt + WD;
    unsigned short* Q = Wot + WD;
    unsigned short* K = Q + MD;
    unsigned short* V = K + MD;   // scratch; used as attention output O
    unsigned short* Vt = V + MD;  // [b*1024 + d][s] — written DIRECTLY by mm_k
    float* ct = (float*)(Vt + MD);
    float* st = ct + S_LEN * 32;
    unsigned short* O = V;
    // split-K partial for Wo: 16 MB fp32 over the dead Q+K regions.
    float* P1 = (float*)Q;
    // attn kv-split partials: 14.2 MB over dead xb+Wqt+Wkt+Wvt (dead after
    // QKV mm; Wo mm reads only O (=V region) and Wot).
    float* Ub = (float*)xb;                 // 384 slots x 8192 floats (12.6 MB)
    float* MLb = Ub + (size_t)384 * 8192;   // 384 slots x 1024 floats (1.6 MB)

    // fused preprocessing: cast + rope tables + weight transposes
    prep_k<<<dim3(3328), dim3(256), 0, stream>>>(x, xb, tokpos, ct, st,
                                                 Wq, Wk, Wv, Wo, Wqt, Wkt, Wvt, Wot);

    // Q (RoPE * 0.125/ln2), K (RoPE), V -> Vt transposed via LDS; 256^2 tiles
    mm_k<<<dim3(16, 4, 3), dim3(512), 0, stream>>>(xb, Wqt, Wkt, Wvt,
                                                   (void*)Q, (void*)K, (void*)Vt, ct, st, 0);
    // kv-split flash attention (704 uniform-ish slices) + exact merge
    attn_k<<<dim3(704), dim3(512), 0, stream>>>(Q, K, Vt, O, Ub, MLb);
    mrg_k<<<dim3(192), dim3(256), 0, stream>>>(Ub, MLb, O);
    // output projection: split-K=2 (128 blocks), plain fp32 stores, reduce
    mm_k<<<dim3(16, 4, 2), dim3(512), 0, stream>>>(O, Wot, Wot, Wot,
                                                   (void*)out, (void*)P1, (void*)P1, ct, st, 1);
    add_k<<<dim3(2048), dim3(256), 0, stream>>>(out, P1);
}